// Round 5
// baseline (161.578 us; speedup 1.0000x reference)
//
#include <hip/hip_runtime.h>

#define B 16384
#define N_SPARSE 16
#define N_VARLEN 4
#define L 50
#define V 1000000
#define ROW (N_SPARSE + N_VARLEN * L)   // 216 ids per row
#define OUT_W (N_SPARSE + N_VARLEN)     // 20 floats per row
#define KLANES 8                        // lanes cooperating per (row, varlen feature)
#define NITER 7                         // ceil(L / KLANES), uniform trip count

// Blocks [0, 1024):    sparse gathers (launched FIRST so their cold HBM misses
//                      overlap varlen work instead of tailing). Non-temporal.
// Blocks [1024, 3072): varlen pooling. Each block reads its PHYSICAL die id
//                      via s_getreg(HW_REG_XCC_ID) (HW-verified, learn_hip m09)
//                      and serves table f = xcc&3, rows-half = xcc>>2, pulling
//                      32-row slots from a per-XCD atomic pool in d_ws. This
//                      pins each 4MB varlen table to one XCD's 4MB L2 without
//                      assuming any blockIdx->XCD mapping.
#define SPARSE_BLOCKS 1024
#define VARLEN_BLOCKS 2048
#define SLOTS_PER_XCD 256               // x 32 rows = 8192 = B/2 rows per (f,half)

__global__ __launch_bounds__(256) void emb_gather_pool_kernel(
    const int* __restrict__ X,
    const float* __restrict__ sparse_tables,
    const float* __restrict__ varlen_tables,
    float* __restrict__ out,
    int* __restrict__ xcd_pool)          // 8 ints, zeroed before launch
{
    const int bid = blockIdx.x;
    const int t   = threadIdx.x;

    if (bid < SPARSE_BLOCKS) {
        // ---- sparse single gathers, fully streaming (non-temporal) ----
        const int rl  = t >> 4;                // row within block [0,16)
        const int j   = t & 15;                // sparse feature
        const int row = bid * 16 + rl;

        const int   id = __builtin_nontemporal_load(X + row * ROW + j);
        const float v  = __builtin_nontemporal_load(sparse_tables + (long)j * V + id);
        __builtin_nontemporal_store(v, out + row * OUT_W + j);
        return;
    }

    // ---- varlen masked-mean pooling, pinned to the PHYSICAL XCD ----
    unsigned int xcc;
    asm volatile("s_getreg_b32 %0, hwreg(HW_REG_XCC_ID)" : "=s"(xcc));
    xcc &= 7;
    const int f    = xcc & 3;            // this XCD serves table f
    const int half = xcc >> 2;           // and this half of the rows
    const float* tab = varlen_tables + (long)f * V;

    __shared__ int s_slot;
    for (;;) {
        if (t == 0) s_slot = atomicAdd(xcd_pool + xcc, 1);
        __syncthreads();
        const int slot = s_slot;
        __syncthreads();
        if (slot >= SLOTS_PER_XCD) break;

        const int task = t >> 3;         // row within slot [0,32)
        const int lane = t & (KLANES - 1);
        const int row  = half * (B / 2) + slot * 32 + task;
        const int* ids = X + row * ROW + N_SPARSE + f * L;

        // Phase 1: issue ALL id loads (coalesced, streamed once).
        // OOB slots (l >= 50) get id=0 -> nullified by the mask (exact).
        int id[NITER];
        #pragma unroll
        for (int k = 0; k < NITER; ++k) {
            const int l = lane + k * KLANES;
            id[k] = (l < L) ? __builtin_nontemporal_load(ids + l) : 0;
        }

        // Phase 2: issue ALL table gathers (kept resident in this XCD's L2).
        float v[NITER];
        #pragma unroll
        for (int k = 0; k < NITER; ++k) {
            v[k] = tab[id[k]];
        }

        // Phase 3: branch-free masked accumulate.
        float sum = 0.0f;
        float cnt = 0.0f;
        #pragma unroll
        for (int k = 0; k < NITER; ++k) {
            const float m = (id[k] != 0) ? 1.0f : 0.0f;
            sum = fmaf(m, v[k], sum);
            cnt += m;
        }

        // Reduce across the aligned 8-lane group.
        #pragma unroll
        for (int off = 1; off < KLANES; off <<= 1) {
            sum += __shfl_xor(sum, off);
            cnt += __shfl_xor(cnt, off);
        }

        if (lane == 0) {
            __builtin_nontemporal_store(sum / (cnt + 1e-8f),
                                        out + row * OUT_W + N_SPARSE + f);
        }
    }
}

extern "C" void kernel_launch(void* const* d_in, const int* in_sizes, int n_in,
                              void* d_out, int out_size, void* d_ws, size_t ws_size,
                              hipStream_t stream) {
    const int*   X             = (const int*)  d_in[0];
    const float* sparse_tables = (const float*)d_in[1];
    const float* varlen_tables = (const float*)d_in[2];
    float*       out           = (float*)d_out;
    int*         xcd_pool      = (int*)d_ws;

    hipMemsetAsync(xcd_pool, 0, 8 * sizeof(int), stream);  // capture-legal

    const int grid  = SPARSE_BLOCKS + VARLEN_BLOCKS;   // 3072
    const int block = 256;

    emb_gather_pool_kernel<<<grid, block, 0, stream>>>(X, sparse_tables, varlen_tables,
                                                       out, xcd_pool);
}

// Round 6
// 131.136 us; speedup vs baseline: 1.2321x; 1.2321x over previous
//
#include <hip/hip_runtime.h>

#define B 16384
#define N_SPARSE 16
#define N_VARLEN 4
#define L 50
#define V 1000000
#define ROW (N_SPARSE + N_VARLEN * L)   // 216 ids per row
#define OUT_W (N_SPARSE + N_VARLEN)     // 20 floats per row
#define KLANES 4                        // lanes per (row, varlen feature) task
#define NITER 13                        // ceil(L / KLANES), uniform trip count

// Structure lesson (R4 vs R5): straight-line blocks with max in-flight gathers
// beat perfect-locality-but-serialized (atomic pool) by 2x. This op is
// outstanding-miss bound, not bytes-bound (R5 measured FETCH=47MB = compulsory
// floor). So: no atomics, no syncthreads, static bid%8 XCD pinning.
//
// Grid (2048 blocks = exactly full residency: 8 blocks/CU x 256 CU):
//   blocks [0, 1024):    varlen pooling, table f = bid&3 pinned to XCD bid&7
//                        (two XCDs per table), KLANES=4 -> 13 outstanding
//                        random gathers per lane.
//   blocks [1024, 2048): sparse gathers, non-temporal (no L2 pollution).
#define VARLEN_BLOCKS 1024
#define SPARSE_BLOCKS 1024

__global__ __launch_bounds__(256) void emb_gather_pool_kernel(
    const int* __restrict__ X,
    const float* __restrict__ sparse_tables,
    const float* __restrict__ varlen_tables,
    float* __restrict__ out)
{
    const int bid = blockIdx.x;
    const int t   = threadIdx.x;

    if (bid < VARLEN_BLOCKS) {
        // ---- varlen masked-mean pooling, XCD-pinned per table ----
        const int xcd  = bid & 7;
        const int f    = xcd & 3;        // table f on XCDs f and f+4
        const int half = xcd >> 2;       // which half of the rows
        const int slot = bid >> 3;       // [0,128) row-chunk within (f, half)
        const int task = t >> 2;         // [0,64) row within block
        const int lane = t & (KLANES - 1);
        const int row  = half * (B / 2) + slot * 64 + task;

        const int*   ids = X + row * ROW + N_SPARSE + f * L;
        const float* tab = varlen_tables + (long)f * V;

        // Phase 1: issue ALL id loads (independent, streamed once).
        // OOB slots (l >= 50) get id=0 -> nullified by the mask (exact).
        int id[NITER];
        #pragma unroll
        for (int k = 0; k < NITER; ++k) {
            const int l = lane + k * KLANES;
            id[k] = (l < L) ? __builtin_nontemporal_load(ids + l) : 0;
        }

        // Phase 2: issue ALL table gathers (13 outstanding misses per lane).
        float v[NITER];
        #pragma unroll
        for (int k = 0; k < NITER; ++k) {
            v[k] = tab[id[k]];           // normal load: lines stay in this XCD's L2
        }

        // Phase 3: branch-free masked accumulate.
        float sum = 0.0f;
        float cnt = 0.0f;
        #pragma unroll
        for (int k = 0; k < NITER; ++k) {
            const float m = (id[k] != 0) ? 1.0f : 0.0f;
            sum = fmaf(m, v[k], sum);
            cnt += m;
        }

        // Reduce across the aligned 4-lane group.
        #pragma unroll
        for (int off = 1; off < KLANES; off <<= 1) {
            sum += __shfl_xor(sum, off);
            cnt += __shfl_xor(cnt, off);
        }

        if (lane == 0) {
            __builtin_nontemporal_store(sum / (cnt + 1e-8f),
                                        out + row * OUT_W + N_SPARSE + f);
        }
    } else {
        // ---- sparse single gathers, fully streaming (non-temporal) ----
        const int sb  = bid - VARLEN_BLOCKS;   // [0,1024)
        const int rl  = t >> 4;                // row within block [0,16)
        const int j   = t & 15;                // sparse feature
        const int row = sb * 16 + rl;

        const int   id = __builtin_nontemporal_load(X + row * ROW + j);
        const float v  = __builtin_nontemporal_load(sparse_tables + (long)j * V + id);
        __builtin_nontemporal_store(v, out + row * OUT_W + j);
    }
}

extern "C" void kernel_launch(void* const* d_in, const int* in_sizes, int n_in,
                              void* d_out, int out_size, void* d_ws, size_t ws_size,
                              hipStream_t stream) {
    const int*   X             = (const int*)  d_in[0];
    const float* sparse_tables = (const float*)d_in[1];
    const float* varlen_tables = (const float*)d_in[2];
    float*       out           = (float*)d_out;

    const int grid  = VARLEN_BLOCKS + SPARSE_BLOCKS;   // 2048 = full residency
    const int block = 256;

    emb_gather_pool_kernel<<<grid, block, 0, stream>>>(X, sparse_tables, varlen_tables, out);
}

// Round 8
// 126.485 us; speedup vs baseline: 1.2774x; 1.0368x over previous
//
#include <hip/hip_runtime.h>

#define B 16384
#define N_SPARSE 16
#define N_VARLEN 4
#define L 50
#define V 1000000
#define ROW (N_SPARSE + N_VARLEN * L)   // 216 ids per row
#define OUT_W (N_SPARSE + N_VARLEN)     // 20 floats per row
#define KLANES 8                        // lanes cooperating per (row, varlen feature)

// Model (R1-R6): this op is bound by the per-CU vector-memory request pipe
// (unique-line lane requests through TA/TCP + MSHR x L2-hit latency), NOT by
// bytes (R5: FETCH=47MB = compulsory floor) and NOT by wave-level ILP
// (R4/R6 neutral). So this round minimizes LANE REQUESTS:
//  - ids 0..47 via 3x 8B vector loads per lane (coalesced, always valid)
//  - ids 48..49 via one exec-predicated scalar load (lanes 0..1 only)
//  - phase-2 gathers exec-predicated: exactly 50 gathers per task, no OOB
//    waste (masked-off lanes issue no TA transaction) vs R4's 56.
// Grid: R4's proven layout. varlen first, XCD-pinned (bid&7); sparse last, nt.
#define VARLEN_BLOCKS 2048
#define SPARSE_BLOCKS 1024
#define NVEC 3                          // 8B id loads per lane (ids 0..47)
#define NID  7                          // id slots per lane (6 vec + 1 tail)

typedef int v2i __attribute__((ext_vector_type(2)));   // builtin-legal 8B vector

__global__ __launch_bounds__(256) void emb_gather_pool_kernel(
    const int* __restrict__ X,
    const float* __restrict__ sparse_tables,
    const float* __restrict__ varlen_tables,
    float* __restrict__ out)
{
    const int bid = blockIdx.x;
    const int t   = threadIdx.x;

    if (bid < VARLEN_BLOCKS) {
        // ---- varlen masked-mean pooling, XCD-pinned per table ----
        const int xcd  = bid & 7;
        const int f    = xcd & 3;        // table f on XCDs f and f+4
        const int half = xcd >> 2;       // which half of the rows
        const int slot = bid >> 3;       // [0,256) row-chunk within (f, half)
        const int task = t >> 3;         // [0,32) row within block
        const int lane = t & (KLANES - 1);
        const int row  = half * (B / 2) + slot * 32 + task;

        const int*   ids = X + row * ROW + N_SPARSE + f * L;
        const float* tab = varlen_tables + (long)f * V;

        // Phase 1: id loads. l = 2*lane + 16*k for k=0..2 covers ids 0..47
        // (8B-aligned: X row base 216*row + 16 + f*50 has even offset, and
        // 2*lane is even). Tail l = 48+lane for lanes 0..1 covers ids 48..49;
        // other lanes get id=0 (nullified by the mask -> exact semantics).
        int id[NID];
        #pragma unroll
        for (int k = 0; k < NVEC; ++k) {
            const v2i w = __builtin_nontemporal_load(
                reinterpret_cast<const v2i*>(ids + 2 * lane + 16 * k));
            id[2 * k]     = w.x;
            id[2 * k + 1] = w.y;
        }
        id[6] = (lane < 2) ? __builtin_nontemporal_load(ids + 48 + lane) : 0;

        // Phase 2: gathers. Slots 0..5 always valid; slot 6 predicated so
        // masked-off lanes issue NO memory transaction.
        float v[NID];
        #pragma unroll
        for (int k = 0; k < 6; ++k) {
            v[k] = tab[id[k]];           // normal load: lines stay in this XCD's L2
        }
        v[6] = 0.0f;
        if (lane < 2) {
            v[6] = tab[id[6]];
        }

        // Phase 3: branch-free masked accumulate.
        float sum = 0.0f;
        float cnt = 0.0f;
        #pragma unroll
        for (int k = 0; k < NID; ++k) {
            const float m = (id[k] != 0) ? 1.0f : 0.0f;
            sum = fmaf(m, v[k], sum);
            cnt += m;
        }

        // Reduce across the aligned 8-lane group.
        #pragma unroll
        for (int off = 1; off < KLANES; off <<= 1) {
            sum += __shfl_xor(sum, off);
            cnt += __shfl_xor(cnt, off);
        }

        if (lane == 0) {
            __builtin_nontemporal_store(sum / (cnt + 1e-8f),
                                        out + row * OUT_W + N_SPARSE + f);
        }
    } else {
        // ---- sparse single gathers, fully streaming (non-temporal) ----
        const int sb  = bid - VARLEN_BLOCKS;   // [0,1024)
        const int rl  = t >> 4;                // row within block [0,16)
        const int j   = t & 15;                // sparse feature
        const int row = sb * 16 + rl;

        const int   id = __builtin_nontemporal_load(X + row * ROW + j);
        const float v  = __builtin_nontemporal_load(sparse_tables + (long)j * V + id);
        __builtin_nontemporal_store(v, out + row * OUT_W + j);
    }
}

extern "C" void kernel_launch(void* const* d_in, const int* in_sizes, int n_in,
                              void* d_out, int out_size, void* d_ws, size_t ws_size,
                              hipStream_t stream) {
    const int*   X             = (const int*)  d_in[0];
    const float* sparse_tables = (const float*)d_in[1];
    const float* varlen_tables = (const float*)d_in[2];
    float*       out           = (float*)d_out;

    const int grid  = VARLEN_BLOCKS + SPARSE_BLOCKS;   // 3072
    const int block = 256;

    emb_gather_pool_kernel<<<grid, block, 0, stream>>>(X, sparse_tables, varlen_tables, out);
}